// Round 8
// baseline (191.946 us; speedup 1.0000x reference)
//
#include <hip/hip_runtime.h>
#include <hip/hip_bf16.h>
#include <math.h>

#define BATCH_N 8
#define SEQ_T   2048
#define DIM_D   1024
#define HS_N    128

using bf16x8_t = __attribute__((ext_vector_type(8))) __bf16;
using bf16x4_t = __attribute__((ext_vector_type(4))) __bf16;
using f32x4_t  = __attribute__((ext_vector_type(4))) float;

__device__ __forceinline__ f32x4_t mfma_16x16x32(bf16x8_t a, bf16x8_t b, f32x4_t c) {
  return __builtin_amdgcn_mfma_f32_16x16x32_bf16(a, b, c, 0, 0, 0);
}

// async global->LDS, 16B/lane; LDS dest = wave-uniform base + lane*16
__device__ __forceinline__ void async_cp16(const void* g, void* l) {
  __builtin_amdgcn_global_load_lds(
      (const __attribute__((address_space(1))) unsigned int*)g,
      (__attribute__((address_space(3))) unsigned int*)l, 16, 0, 0);
}

// ---------------------------------------------------------------------------
// Kernel 0: cast W -> bf16, rows [K:0-127][Q:128-255][V:256-383], Q pre-scaled.
// Also zeroes km (drops the separate hipMemsetAsync dispatch).
// ---------------------------------------------------------------------------
__global__ __launch_bounds__(256) void castw_kernel(
    const float* __restrict__ Wk, const float* __restrict__ Wq,
    const float* __restrict__ Wv, __bf16* __restrict__ Wb,
    unsigned int* __restrict__ km) {
  if (blockIdx.x == 0 && threadIdx.x < 8) km[threadIdx.x] = 0u;
  int idx = blockIdx.x * 256 + threadIdx.x;
  int e   = idx * 4;
  int row = e >> 10;
  int col = e & 1023;
  const float* src;
  float sc = 1.0f;
  if (row < 128) {
    src = Wk + row * DIM_D + col;
  } else if (row < 256) {
    src = Wq + (row - 128) * DIM_D + col;
    sc  = 0.08838834764831845f;  // 1/sqrt(HS) folded into Wq
  } else {
    src = Wv + (row - 256) * DIM_D + col;
  }
  float4 v = *(const float4*)src;
  bf16x4_t o;
  o[0] = (__bf16)(v.x * sc); o[1] = (__bf16)(v.y * sc);
  o[2] = (__bf16)(v.z * sc); o[3] = (__bf16)(v.w * sc);
  *(bf16x4_t*)(Wb + e) = o;
}

// ---------------------------------------------------------------------------
// Kernel 1: projections v8 — A fully LDS-resident.
// Block = 64 m-rows x full N=384, grid 256 (1 block/CU). Two K-phases of 512:
// prologue casts x[64 x 512] fp32->bf16 into LDS once (A = 64 KB), then 16
// BK=32 iterations whose ONLY global dependency is the 24 KB B-chunk
// (double-buffered global_load_lds). Inner iter: 4 A ds_reads + 6 B ds_reads
// + 24 MFMA per wave, no cvt. Swizzles conflict-free (2-way max):
// A 1KB rows: unit ^ (row&7); Bs 64B rows: unit ^ ((row>>1)&3).
// ---------------------------------------------------------------------------
__global__ __launch_bounds__(256) void proj_kernel(
    const float* __restrict__ x, const __bf16* __restrict__ Wb,
    __bf16* __restrict__ Qb, __bf16* __restrict__ Kb, __bf16* __restrict__ Vt) {
  __shared__ __bf16 A[64 * 512];      // 64 KB: one 512-wide K-phase of x
  __shared__ __bf16 Bs[2][384 * 32];  // 24 KB per buf

  const int tid  = threadIdx.x;
  const int lane = tid & 63;
  const int wave = tid >> 6;
  const int lr = lane & 15;
  const int lq = lane >> 4;
  const int m0 = blockIdx.x * 64;

  f32x4_t acc[4][6];
  #pragma unroll
  for (int mt = 0; mt < 4; ++mt)
    #pragma unroll
    for (int nt = 0; nt < 6; ++nt) acc[mt][nt] = (f32x4_t){0.f, 0.f, 0.f, 0.f};

  auto stageB = [&](int bufi, int kt) {
    for (int c = wave; c < 24; c += 4) {     // 16 rows x 64B per call
      const int row = c * 16 + (lane >> 2);
      const int u   = (lane & 3) ^ ((row >> 1) & 3);
      async_cp16(Wb + (size_t)row * DIM_D + kt * 32 + u * 8,
                 &Bs[bufi][c * 512]);
    }
  };

  stageB(0, 0);

  for (int p = 0; p < 2; ++p) {
    __syncthreads();   // phase-0: also covers stageB(0) drain; phase-1: protects A

    // ---- cast this phase's x slab into LDS (once per 16 K-iters) ----
    {
      const int r  = tid >> 2;        // 0..63
      const int qt = tid & 3;
      const float* xs = x + (size_t)(m0 + r) * DIM_D + p * 512;
      __bf16* as = A + r * 512;
      const int sw = r & 7;
      #pragma unroll
      for (int i = 0; i < 16; ++i) {
        const int u = i * 4 + qt;     // 0..63 (16B units within the phase)
        float4 f0 = *(const float4*)(xs + u * 8);
        float4 f1 = *(const float4*)(xs + u * 8 + 4);
        bf16x8_t a;
        a[0] = (__bf16)f0.x; a[1] = (__bf16)f0.y;
        a[2] = (__bf16)f0.z; a[3] = (__bf16)f0.w;
        a[4] = (__bf16)f1.x; a[5] = (__bf16)f1.y;
        a[6] = (__bf16)f1.z; a[7] = (__bf16)f1.w;
        *(bf16x8_t*)(as + ((u ^ sw) * 8)) = a;
      }
    }
    __syncthreads();   // A ready

    for (int kt2 = 0; kt2 < 16; ++kt2) {
      const int kt  = p * 16 + kt2;
      const int cur = kt & 1;
      if (kt + 1 < 32) stageB(cur ^ 1, kt + 1);

      bf16x8_t af[4];
      #pragma unroll
      for (int mt = 0; mt < 4; ++mt) {
        const int ml = mt * 16 + lr;
        const int u  = kt2 * 4 + lq;
        af[mt] = *(const bf16x8_t*)(&A[ml * 512 + ((u ^ (ml & 7)) * 8)]);
      }
      bf16x8_t bfv[6];
      #pragma unroll
      for (int nt = 0; nt < 6; ++nt) {
        const int nl = wave * 96 + nt * 16 + lr;
        bfv[nt] = *(const bf16x8_t*)(&Bs[cur][nl * 32 + ((lq ^ ((nl >> 1) & 3)) * 8)]);
      }
      #pragma unroll
      for (int mt = 0; mt < 4; ++mt)
        #pragma unroll
        for (int nt = 0; nt < 6; ++nt)
          acc[mt][nt] = mfma_16x16x32(af[mt], bfv[nt], acc[mt][nt]);
      __syncthreads();   // drains stageB(kt+1); protects Bs + A-phase reuse
    }
  }

  #pragma unroll
  for (int mt = 0; mt < 4; ++mt) {
    const int t0 = m0 + mt * 16 + lq * 4;
    #pragma unroll
    for (int nt = 0; nt < 6; ++nt) {
      const int nn = wave * 96 + nt * 16 + lr;
      if (nn < 256) {
        __bf16* dst = (nn < 128) ? (Kb + nn) : (Qb + (nn - 128));
        #pragma unroll
        for (int r = 0; r < 4; ++r)
          dst[(size_t)(t0 + r) * HS_N] = (__bf16)acc[mt][nt][r];
      } else {
        const int bb = t0 >> 11;
        const int tl = t0 & 2047;
        bf16x4_t o;
        #pragma unroll
        for (int r = 0; r < 4; ++r) o[r] = (__bf16)acc[mt][nt][r];
        *(bf16x4_t*)(Vt + (size_t)bb * (HS_N * SEQ_T) + (size_t)(nn - 256) * SEQ_T + tl) = o;
      }
    }
  }
}

// ---------------------------------------------------------------------------
// Kernel 1b: per-batch max ||k||^2 (softmax upper bound)
// ---------------------------------------------------------------------------
__global__ __launch_bounds__(256) void knorm_kernel(
    const __bf16* __restrict__ Kb, unsigned int* __restrict__ km) {
  const int t = blockIdx.x * 256 + threadIdx.x;
  const __bf16* kp = Kb + (size_t)t * HS_N;
  float ss = 0.f;
  #pragma unroll
  for (int i = 0; i < 16; ++i) {
    bf16x8_t v = *(const bf16x8_t*)(kp + i * 8);
    #pragma unroll
    for (int j = 0; j < 8; ++j) { float f = (float)v[j]; ss += f * f; }
  }
  #pragma unroll
  for (int off = 1; off < 64; off <<= 1) ss = fmaxf(ss, __shfl_xor(ss, off));
  if ((threadIdx.x & 63) == 0) atomicMax(km + (t >> 11), __float_as_uint(ss));
}

// ---------------------------------------------------------------------------
// Kernel 2: flash attention v6 (unchanged from round 7). Block = 4 waves x
// 32 q-rows sharing the staged K/V chunk; bounded-max softmax; split into 2
// key-halves with additive partial merge. Grid 256.
// ---------------------------------------------------------------------------
__global__ __launch_bounds__(256) void attn_kernel(
    const __bf16* __restrict__ Qb, const __bf16* __restrict__ Kb,
    const __bf16* __restrict__ Vt, const unsigned int* __restrict__ km,
    __bf16* __restrict__ Opart, float* __restrict__ lpart) {
  __shared__ __align__(16) char smem[84480];
  __bf16* KsBase = (__bf16*)smem;                    // 2 x 16 KB
  __bf16* VsBase = (__bf16*)(smem + 32768);          // 2 x 16 KB
  float*  Ofl    = (float*)smem;                     // 128x132 fp32, post-loop

  const int lane = threadIdx.x & 63;
  const int wave = threadIdx.x >> 6;       // 0..3
  const int lr = lane & 15;
  const int lq = lane >> 4;
  const int bid  = blockIdx.x;
  const int b    = bid & 7;                // batch -> XCD pinned
  const int rest = bid >> 3;               // 0..31
  const int jg   = 15 - (rest >> 1);       // heavy-first
  const int h    = rest & 1;               // key half
  const int Q0   = jg * 128;
  const int qa   = Q0 + wave * 32;         // this wave's 32 rows (2 tiles)
  const int nchunks = jg + 1;              // 64-key chunks in this half
  const int kbase   = h * nchunks * 64;

  const __bf16* Qbb = Qb + (size_t)b * (SEQ_T * HS_N);
  const __bf16* Kbb = Kb + (size_t)b * (SEQ_T * HS_N);
  const __bf16* Vbb = Vt + (size_t)b * (HS_N * SEQ_T);
  __bf16* pbA = (__bf16*)(smem + 65536 + (wave * 2 + 0) * 2304);
  __bf16* pbB = (__bf16*)(smem + 65536 + (wave * 2 + 1) * 2304);

  bf16x8_t qf[2][4];
  #pragma unroll
  for (int t = 0; t < 2; ++t)
    #pragma unroll
    for (int ks = 0; ks < 4; ++ks)
      qf[t][ks] = *(const bf16x8_t*)(Qbb + (size_t)(qa + t * 16 + lr) * HS_N
                                     + ks * 32 + lq * 8);

  // fixed per-row softmax bound m = ||q_hat|| * max||k||
  const float km2 = __uint_as_float(km[b]);
  float mrow[2][4];
  #pragma unroll
  for (int t = 0; t < 2; ++t) {
    float qn2 = 0.f;
    #pragma unroll
    for (int ks = 0; ks < 4; ++ks)
      #pragma unroll
      for (int j = 0; j < 8; ++j) { float f = (float)qf[t][ks][j]; qn2 += f * f; }
    qn2 += __shfl_xor(qn2, 16);
    qn2 += __shfl_xor(qn2, 32);
    #pragma unroll
    for (int r2 = 0; r2 < 4; ++r2)
      mrow[t][r2] = sqrtf(__shfl(qn2, lq * 4 + r2) * km2);
  }

  f32x4_t Oa[2][8];
  #pragma unroll
  for (int t = 0; t < 2; ++t)
    #pragma unroll
    for (int o = 0; o < 8; ++o) Oa[t][o] = (f32x4_t){0.f, 0.f, 0.f, 0.f};
  float lsum[2][4] = {{0.f,0.f,0.f,0.f},{0.f,0.f,0.f,0.f}};

  auto stage = [&](int bufi, int c) {
    const int kk = kbase + c * 64;
    __bf16* Ks = KsBase + bufi * 8192;
    for (int idx = wave; idx < 32; idx += 4) {
      if (idx < 16) {          // K: 4 rows x 256B per call
        const int row = idx * 4 + (lane >> 4);
        const int u   = (lane & 15) ^ (row & 15);
        async_cp16(Kbb + (size_t)(kk + row) * HS_N + u * 8, Ks + idx * 512);
      } else {                 // V: 8 rows x 128B per call (rows = HS dims)
        const int i2  = idx - 16;
        const int row = i2 * 8 + (lane >> 3);
        const int u   = (lane & 7) ^ (row & 7);
        async_cp16(Vbb + (size_t)row * SEQ_T + kk + u * 8, VsBase + bufi * 8192 + i2 * 512);
      }
    }
  };

  stage(0, 0);
  __syncthreads();

  for (int c = 0; c < nchunks; ++c) {
    const int cur = c & 1;
    if (c + 1 < nchunks) stage(cur ^ 1, c + 1);
    const int kk = kbase + c * 64;
    const __bf16* Ks = KsBase + cur * 8192;
    const __bf16* Vs = VsBase + cur * 8192;

    f32x4_t s0[4], s1[4];
    #pragma unroll
    for (int nt = 0; nt < 4; ++nt) {
      s0[nt] = (f32x4_t){0.f, 0.f, 0.f, 0.f};
      s1[nt] = (f32x4_t){0.f, 0.f, 0.f, 0.f};
    }
    #pragma unroll
    for (int ks = 0; ks < 4; ++ks)
      #pragma unroll
      for (int nt = 0; nt < 4; ++nt) {
        bf16x8_t kf = *(const bf16x8_t*)(
            &Ks[(nt * 16 + lr) * 128 + (((ks * 4 + lq) ^ lr) * 8)]);
        s0[nt] = mfma_16x16x32(qf[0][ks], kf, s0[nt]);
        s1[nt] = mfma_16x16x32(qf[1][ks], kf, s1[nt]);
      }
    const int q0a = qa, q0b = qa + 16;
    if (kk + 63 > q0a) {
      #pragma unroll
      for (int nt = 0; nt < 4; ++nt) {
        const int col = kk + nt * 16 + lr;
        #pragma unroll
        for (int r2 = 0; r2 < 4; ++r2)
          if (col > q0a + lq * 4 + r2) s0[nt][r2] = -INFINITY;
      }
    }
    if (kk + 63 > q0b) {
      #pragma unroll
      for (int nt = 0; nt < 4; ++nt) {
        const int col = kk + nt * 16 + lr;
        #pragma unroll
        for (int r2 = 0; r2 < 4; ++r2)
          if (col > q0b + lq * 4 + r2) s1[nt][r2] = -INFINITY;
      }
    }

    #pragma unroll
    for (int r2 = 0; r2 < 4; ++r2) {
      float a0 = __expf(s0[0][r2] - mrow[0][r2]);
      float a1 = __expf(s0[1][r2] - mrow[0][r2]);
      float a2 = __expf(s0[2][r2] - mrow[0][r2]);
      float a3 = __expf(s0[3][r2] - mrow[0][r2]);
      s0[0][r2] = a0; s0[1][r2] = a1; s0[2][r2] = a2; s0[3][r2] = a3;
      lsum[0][r2] += (a0 + a1) + (a2 + a3);
      float b0 = __expf(s1[0][r2] - mrow[1][r2]);
      float b1 = __expf(s1[1][r2] - mrow[1][r2]);
      float b2 = __expf(s1[2][r2] - mrow[1][r2]);
      float b3 = __expf(s1[3][r2] - mrow[1][r2]);
      s1[0][r2] = b0; s1[1][r2] = b1; s1[2][r2] = b2; s1[3][r2] = b3;
      lsum[1][r2] += (b0 + b1) + (b2 + b3);
    }

    #pragma unroll
    for (int nt = 0; nt < 4; ++nt)
      #pragma unroll
      for (int r2 = 0; r2 < 4; ++r2) {
        pbA[(lq * 4 + r2) * 72 + nt * 16 + lr] = (__bf16)s0[nt][r2];
        pbB[(lq * 4 + r2) * 72 + nt * 16 + lr] = (__bf16)s1[nt][r2];
      }

    #pragma unroll
    for (int k2 = 0; k2 < 2; ++k2) {
      bf16x8_t afrA = *(const bf16x8_t*)(pbA + lr * 72 + k2 * 32 + lq * 8);
      bf16x8_t afrB = *(const bf16x8_t*)(pbB + lr * 72 + k2 * 32 + lq * 8);
      #pragma unroll
      for (int o = 0; o < 8; ++o) {
        bf16x8_t vfr = *(const bf16x8_t*)(
            &Vs[(o * 16 + lr) * 64 + (((k2 * 4 + lq) ^ (lr & 7)) * 8)]);
        Oa[0][o] = mfma_16x16x32(afrA, vfr, Oa[0][o]);
        Oa[1][o] = mfma_16x16x32(afrB, vfr, Oa[1][o]);
      }
    }
    __syncthreads();
  }

  #pragma unroll
  for (int t = 0; t < 2; ++t)
    #pragma unroll
    for (int r2 = 0; r2 < 4; ++r2) {
      float v = lsum[t][r2];
      v += __shfl_xor(v, 1);
      v += __shfl_xor(v, 2);
      v += __shfl_xor(v, 4);
      v += __shfl_xor(v, 8);
      if (lr == 0)
        lpart[bid * 128 + wave * 32 + t * 16 + lq * 4 + r2] = v;
    }

  #pragma unroll
  for (int t = 0; t < 2; ++t)
    #pragma unroll
    for (int o = 0; o < 8; ++o)
      #pragma unroll
      for (int r2 = 0; r2 < 4; ++r2)
        Ofl[(wave * 32 + t * 16 + lq * 4 + r2) * 132 + o * 16 + lr] = Oa[t][o][r2];
  __syncthreads();

  {
    const int row = threadIdx.x >> 1;
    const int cb  = (threadIdx.x & 1) * 64;
    __bf16* dst = Opart + ((size_t)bid * 128 + row) * 128 + cb;
    #pragma unroll
    for (int g2 = 0; g2 < 16; ++g2) {
      float4 f = *(const float4*)(&Ofl[row * 132 + cb + g2 * 4]);
      bf16x4_t o;
      o[0] = (__bf16)f.x; o[1] = (__bf16)f.y; o[2] = (__bf16)f.z; o[3] = (__bf16)f.w;
      *(bf16x4_t*)(dst + g2 * 4) = o;
    }
  }
}

// ---------------------------------------------------------------------------
// Kernel 3: merge the 2 key-halves: out = (O_h0 + O_h1) / (l_h0 + l_h1)
// ---------------------------------------------------------------------------
__global__ __launch_bounds__(256) void merge_kernel(
    const __bf16* __restrict__ Opart, const float* __restrict__ lpart,
    float* __restrict__ out) {
  const int idx = blockIdx.x * 256 + threadIdx.x;   // 524288 threads
  const int row = idx >> 5;                         // global row 0..16383
  const int c4  = (idx & 31) * 4;
  const int b   = row >> 11;
  const int tl  = row & 2047;
  const int jg  = tl >> 7;
  const int lrow = tl & 127;
  const int s0  = b + 8 * (2 * (15 - jg));          // h=0 slot (bid)
  const int s1  = s0 + 8;                           // h=1 slot
  bf16x4_t a = *(const bf16x4_t*)(Opart + ((size_t)s0 * 128 + lrow) * 128 + c4);
  bf16x4_t c = *(const bf16x4_t*)(Opart + ((size_t)s1 * 128 + lrow) * 128 + c4);
  const float l = lpart[s0 * 128 + lrow] + lpart[s1 * 128 + lrow];
  const float inv = 1.0f / l;
  float4 o;
  o.x = ((float)a[0] + (float)c[0]) * inv;
  o.y = ((float)a[1] + (float)c[1]) * inv;
  o.z = ((float)a[2] + (float)c[2]) * inv;
  o.w = ((float)a[3] + (float)c[3]) * inv;
  *(float4*)(out + (size_t)row * HS_N + c4) = o;
}

// ---------------------------------------------------------------------------
extern "C" void kernel_launch(void* const* d_in, const int* in_sizes, int n_in,
                              void* d_out, int out_size, void* d_ws, size_t ws_size,
                              hipStream_t stream) {
  const float* x  = (const float*)d_in[0];
  const float* Wk = (const float*)d_in[1];
  const float* Wq = (const float*)d_in[2];
  const float* Wv = (const float*)d_in[3];
  float* out = (float*)d_out;

  char* ws = (char*)d_ws;
  __bf16* Wb = (__bf16*)ws;                          //   786432 B
  __bf16* Qb = (__bf16*)(ws + 786432);               //  4194304 B
  __bf16* Kb = (__bf16*)(ws + 786432 + 4194304);     //  4194304 B
  __bf16* Vt = (__bf16*)(ws + 786432 + 8388608);     //  4194304 B
  unsigned int* km = (unsigned int*)(ws + 13369344); //       32 B
  __bf16* Opart = (__bf16*)(ws + 13369600);          //  8388608 B (256x128x128)
  float*  lpart = (float*)(ws + 21758208);           //   131072 B  (~21.9 MB total)

  castw_kernel<<<384, 256, 0, stream>>>(Wk, Wq, Wv, Wb, km);
  proj_kernel<<<256, 256, 0, stream>>>(x, Wb, Qb, Kb, Vt);
  knorm_kernel<<<64, 256, 0, stream>>>(Kb, km);
  attn_kernel<<<256, 256, 0, stream>>>(Qb, Kb, Vt, km, Opart, lpart);
  merge_kernel<<<2048, 256, 0, stream>>>(Opart, lpart, out);
}

// Round 9
// 183.167 us; speedup vs baseline: 1.0479x; 1.0479x over previous
//
#include <hip/hip_runtime.h>
#include <hip/hip_bf16.h>
#include <math.h>

#define BATCH_N 8
#define SEQ_T   2048
#define DIM_D   1024
#define HS_N    128

using bf16x8_t = __attribute__((ext_vector_type(8))) __bf16;
using bf16x4_t = __attribute__((ext_vector_type(4))) __bf16;
using f32x4_t  = __attribute__((ext_vector_type(4))) float;

__device__ __forceinline__ f32x4_t mfma_16x16x32(bf16x8_t a, bf16x8_t b, f32x4_t c) {
  return __builtin_amdgcn_mfma_f32_16x16x32_bf16(a, b, c, 0, 0, 0);
}

// async global->LDS, 16B/lane; LDS dest = wave-uniform base + lane*16
__device__ __forceinline__ void async_cp16(const void* g, void* l) {
  __builtin_amdgcn_global_load_lds(
      (const __attribute__((address_space(1))) unsigned int*)g,
      (__attribute__((address_space(3))) unsigned int*)l, 16, 0, 0);
}

// ---------------------------------------------------------------------------
// Kernel 0: cast W -> bf16, rows [K:0-127][Q:128-255][V:256-383], Q pre-scaled.
// Also zeroes km.
// ---------------------------------------------------------------------------
__global__ __launch_bounds__(256) void castw_kernel(
    const float* __restrict__ Wk, const float* __restrict__ Wq,
    const float* __restrict__ Wv, __bf16* __restrict__ Wb,
    unsigned int* __restrict__ km) {
  if (blockIdx.x == 0 && threadIdx.x < 8) km[threadIdx.x] = 0u;
  int idx = blockIdx.x * 256 + threadIdx.x;
  int e   = idx * 4;
  int row = e >> 10;
  int col = e & 1023;
  const float* src;
  float sc = 1.0f;
  if (row < 128) {
    src = Wk + row * DIM_D + col;
  } else if (row < 256) {
    src = Wq + (row - 128) * DIM_D + col;
    sc  = 0.08838834764831845f;  // 1/sqrt(HS) folded into Wq
  } else {
    src = Wv + (row - 256) * DIM_D + col;
  }
  float4 v = *(const float4*)src;
  bf16x4_t o;
  o[0] = (__bf16)(v.x * sc); o[1] = (__bf16)(v.y * sc);
  o[2] = (__bf16)(v.z * sc); o[3] = (__bf16)(v.w * sc);
  *(bf16x4_t*)(Wb + e) = o;
}

// ---------------------------------------------------------------------------
// Kernel 1: projections v9 — A LDS-resident AND 2 blocks/CU.
// Block = 32 m-rows x full N=384, grid 512 (2 blocks/CU; co-resident block
// hides the per-iter barrier drain that killed v8). Two 512-wide K-phases:
// cast x[32x512] fp32->bf16 into LDS once per phase (A = 32 KB), then 16
// BK=32 iters whose only global dependency is the 24 KB dbuf B-chunk.
// LDS = 32768 (A) + 2x24576 (B) = 81920 B exactly -> 2 blocks/CU.
// Inner iter/wave: 2 A ds_reads + 6 B ds_reads + 12 MFMA, no cvt.
// Swizzles (<=2-way, free): A 1KB rows unit^(row&7); B 64B rows unit^((row>>1)&3).
// ---------------------------------------------------------------------------
__global__ __launch_bounds__(256, 2) void proj_kernel(
    const float* __restrict__ x, const __bf16* __restrict__ Wb,
    __bf16* __restrict__ Qb, __bf16* __restrict__ Kb, __bf16* __restrict__ Vt) {
  __shared__ __align__(16) char psmem[81920];
  __bf16* A = (__bf16*)psmem;                       // 32 x 512 bf16 = 32 KB

  const int tid  = threadIdx.x;
  const int lane = tid & 63;
  const int wave = tid >> 6;
  const int lr = lane & 15;
  const int lq = lane >> 4;
  const int m0 = blockIdx.x * 32;

  f32x4_t acc[2][6];
  #pragma unroll
  for (int mt = 0; mt < 2; ++mt)
    #pragma unroll
    for (int nt = 0; nt < 6; ++nt) acc[mt][nt] = (f32x4_t){0.f, 0.f, 0.f, 0.f};

  auto stageB = [&](int bufi, int kt) {
    __bf16* Bs = (__bf16*)(psmem + 32768 + bufi * 24576);
    for (int c = wave; c < 24; c += 4) {     // 16 rows x 64B per call
      const int row = c * 16 + (lane >> 2);
      const int u   = (lane & 3) ^ ((row >> 1) & 3);
      async_cp16(Wb + (size_t)row * DIM_D + kt * 32 + u * 8, Bs + c * 512);
    }
  };

  stageB(0, 0);

  for (int p = 0; p < 2; ++p) {
    __syncthreads();   // p=0: drains stageB(0); p=1: protects A reuse

    // ---- cast this phase's x slab into LDS (once per 16 K-iters) ----
    {
      const int r  = tid >> 3;        // 0..31
      const int t  = tid & 7;
      const float* xs = x + (size_t)(m0 + r) * DIM_D + p * 512;
      __bf16* as = A + r * 512;
      const int sw = r & 7;
      #pragma unroll
      for (int i = 0; i < 8; ++i) {
        const int u = t + 8 * i;      // 16B units (8 bf16) within the phase
        float4 f0 = *(const float4*)(xs + u * 8);
        float4 f1 = *(const float4*)(xs + u * 8 + 4);
        bf16x8_t a;
        a[0] = (__bf16)f0.x; a[1] = (__bf16)f0.y;
        a[2] = (__bf16)f0.z; a[3] = (__bf16)f0.w;
        a[4] = (__bf16)f1.x; a[5] = (__bf16)f1.y;
        a[6] = (__bf16)f1.z; a[7] = (__bf16)f1.w;
        *(bf16x8_t*)(as + ((u ^ sw) * 8)) = a;
      }
    }
    __syncthreads();   // A ready

    for (int kt2 = 0; kt2 < 16; ++kt2) {
      const int kt  = p * 16 + kt2;
      const int cur = kt & 1;
      if (kt + 1 < 32) stageB(cur ^ 1, kt + 1);
      const __bf16* Bs = (const __bf16*)(psmem + 32768 + cur * 24576);

      bf16x8_t af[2];
      #pragma unroll
      for (int mt = 0; mt < 2; ++mt) {
        const int ml = mt * 16 + lr;
        const int u  = kt2 * 4 + lq;
        af[mt] = *(const bf16x8_t*)(&A[ml * 512 + ((u ^ (ml & 7)) * 8)]);
      }
      bf16x8_t bfv[6];
      #pragma unroll
      for (int nt = 0; nt < 6; ++nt) {
        const int nl = wave * 96 + nt * 16 + lr;
        bfv[nt] = *(const bf16x8_t*)(&Bs[nl * 32 + ((lq ^ ((nl >> 1) & 3)) * 8)]);
      }
      #pragma unroll
      for (int mt = 0; mt < 2; ++mt)
        #pragma unroll
        for (int nt = 0; nt < 6; ++nt)
          acc[mt][nt] = mfma_16x16x32(af[mt], bfv[nt], acc[mt][nt]);
      __syncthreads();   // drains stageB(kt+1); protects Bs buffer reuse
    }
  }

  #pragma unroll
  for (int mt = 0; mt < 2; ++mt) {
    const int t0 = m0 + mt * 16 + lq * 4;
    #pragma unroll
    for (int nt = 0; nt < 6; ++nt) {
      const int nn = wave * 96 + nt * 16 + lr;
      if (nn < 256) {
        __bf16* dst = (nn < 128) ? (Kb + nn) : (Qb + (nn - 128));
        #pragma unroll
        for (int r = 0; r < 4; ++r)
          dst[(size_t)(t0 + r) * HS_N] = (__bf16)acc[mt][nt][r];
      } else {
        const int bb = t0 >> 11;
        const int tl = t0 & 2047;
        bf16x4_t o;
        #pragma unroll
        for (int r = 0; r < 4; ++r) o[r] = (__bf16)acc[mt][nt][r];
        *(bf16x4_t*)(Vt + (size_t)bb * (HS_N * SEQ_T) + (size_t)(nn - 256) * SEQ_T + tl) = o;
      }
    }
  }
}

// ---------------------------------------------------------------------------
// Kernel 1b: per-batch max ||k||^2 (softmax upper bound)
// ---------------------------------------------------------------------------
__global__ __launch_bounds__(256) void knorm_kernel(
    const __bf16* __restrict__ Kb, unsigned int* __restrict__ km) {
  const int t = blockIdx.x * 256 + threadIdx.x;
  const __bf16* kp = Kb + (size_t)t * HS_N;
  float ss = 0.f;
  #pragma unroll
  for (int i = 0; i < 16; ++i) {
    bf16x8_t v = *(const bf16x8_t*)(kp + i * 8);
    #pragma unroll
    for (int j = 0; j < 8; ++j) { float f = (float)v[j]; ss += f * f; }
  }
  #pragma unroll
  for (int off = 1; off < 64; off <<= 1) ss = fmaxf(ss, __shfl_xor(ss, off));
  if ((threadIdx.x & 63) == 0) atomicMax(km + (t >> 11), __float_as_uint(ss));
}

// ---------------------------------------------------------------------------
// Kernel 2: flash attention v6 (unchanged). Block = 4 waves x 32 q-rows
// sharing the staged K/V chunk; bounded-max softmax; 2 key-halves with
// additive partial merge. Grid 256.
// ---------------------------------------------------------------------------
__global__ __launch_bounds__(256) void attn_kernel(
    const __bf16* __restrict__ Qb, const __bf16* __restrict__ Kb,
    const __bf16* __restrict__ Vt, const unsigned int* __restrict__ km,
    __bf16* __restrict__ Opart, float* __restrict__ lpart) {
  __shared__ __align__(16) char smem[84480];
  __bf16* KsBase = (__bf16*)smem;                    // 2 x 16 KB
  __bf16* VsBase = (__bf16*)(smem + 32768);          // 2 x 16 KB
  float*  Ofl    = (float*)smem;                     // 128x132 fp32, post-loop

  const int lane = threadIdx.x & 63;
  const int wave = threadIdx.x >> 6;       // 0..3
  const int lr = lane & 15;
  const int lq = lane >> 4;
  const int bid  = blockIdx.x;
  const int b    = bid & 7;                // batch -> XCD pinned
  const int rest = bid >> 3;               // 0..31
  const int jg   = 15 - (rest >> 1);       // heavy-first
  const int h    = rest & 1;               // key half
  const int Q0   = jg * 128;
  const int qa   = Q0 + wave * 32;         // this wave's 32 rows (2 tiles)
  const int nchunks = jg + 1;              // 64-key chunks in this half
  const int kbase   = h * nchunks * 64;

  const __bf16* Qbb = Qb + (size_t)b * (SEQ_T * HS_N);
  const __bf16* Kbb = Kb + (size_t)b * (SEQ_T * HS_N);
  const __bf16* Vbb = Vt + (size_t)b * (HS_N * SEQ_T);
  __bf16* pbA = (__bf16*)(smem + 65536 + (wave * 2 + 0) * 2304);
  __bf16* pbB = (__bf16*)(smem + 65536 + (wave * 2 + 1) * 2304);

  bf16x8_t qf[2][4];
  #pragma unroll
  for (int t = 0; t < 2; ++t)
    #pragma unroll
    for (int ks = 0; ks < 4; ++ks)
      qf[t][ks] = *(const bf16x8_t*)(Qbb + (size_t)(qa + t * 16 + lr) * HS_N
                                     + ks * 32 + lq * 8);

  const float km2 = __uint_as_float(km[b]);
  float mrow[2][4];
  #pragma unroll
  for (int t = 0; t < 2; ++t) {
    float qn2 = 0.f;
    #pragma unroll
    for (int ks = 0; ks < 4; ++ks)
      #pragma unroll
      for (int j = 0; j < 8; ++j) { float f = (float)qf[t][ks][j]; qn2 += f * f; }
    qn2 += __shfl_xor(qn2, 16);
    qn2 += __shfl_xor(qn2, 32);
    #pragma unroll
    for (int r2 = 0; r2 < 4; ++r2)
      mrow[t][r2] = sqrtf(__shfl(qn2, lq * 4 + r2) * km2);
  }

  f32x4_t Oa[2][8];
  #pragma unroll
  for (int t = 0; t < 2; ++t)
    #pragma unroll
    for (int o = 0; o < 8; ++o) Oa[t][o] = (f32x4_t){0.f, 0.f, 0.f, 0.f};
  float lsum[2][4] = {{0.f,0.f,0.f,0.f},{0.f,0.f,0.f,0.f}};

  auto stage = [&](int bufi, int c) {
    const int kk = kbase + c * 64;
    __bf16* Ks = KsBase + bufi * 8192;
    for (int idx = wave; idx < 32; idx += 4) {
      if (idx < 16) {          // K: 4 rows x 256B per call
        const int row = idx * 4 + (lane >> 4);
        const int u   = (lane & 15) ^ (row & 15);
        async_cp16(Kbb + (size_t)(kk + row) * HS_N + u * 8, Ks + idx * 512);
      } else {                 // V: 8 rows x 128B per call (rows = HS dims)
        const int i2  = idx - 16;
        const int row = i2 * 8 + (lane >> 3);
        const int u   = (lane & 7) ^ (row & 7);
        async_cp16(Vbb + (size_t)row * SEQ_T + kk + u * 8, VsBase + bufi * 8192 + i2 * 512);
      }
    }
  };

  stage(0, 0);
  __syncthreads();

  for (int c = 0; c < nchunks; ++c) {
    const int cur = c & 1;
    if (c + 1 < nchunks) stage(cur ^ 1, c + 1);
    const int kk = kbase + c * 64;
    const __bf16* Ks = KsBase + cur * 8192;
    const __bf16* Vs = VsBase + cur * 8192;

    f32x4_t s0[4], s1[4];
    #pragma unroll
    for (int nt = 0; nt < 4; ++nt) {
      s0[nt] = (f32x4_t){0.f, 0.f, 0.f, 0.f};
      s1[nt] = (f32x4_t){0.f, 0.f, 0.f, 0.f};
    }
    #pragma unroll
    for (int ks = 0; ks < 4; ++ks)
      #pragma unroll
      for (int nt = 0; nt < 4; ++nt) {
        bf16x8_t kf = *(const bf16x8_t*)(
            &Ks[(nt * 16 + lr) * 128 + (((ks * 4 + lq) ^ lr) * 8)]);
        s0[nt] = mfma_16x16x32(qf[0][ks], kf, s0[nt]);
        s1[nt] = mfma_16x16x32(qf[1][ks], kf, s1[nt]);
      }
    const int q0a = qa, q0b = qa + 16;
    if (kk + 63 > q0a) {
      #pragma unroll
      for (int nt = 0; nt < 4; ++nt) {
        const int col = kk + nt * 16 + lr;
        #pragma unroll
        for (int r2 = 0; r2 < 4; ++r2)
          if (col > q0a + lq * 4 + r2) s0[nt][r2] = -INFINITY;
      }
    }
    if (kk + 63 > q0b) {
      #pragma unroll
      for (int nt = 0; nt < 4; ++nt) {
        const int col = kk + nt * 16 + lr;
        #pragma unroll
        for (int r2 = 0; r2 < 4; ++r2)
          if (col > q0b + lq * 4 + r2) s1[nt][r2] = -INFINITY;
      }
    }

    #pragma unroll
    for (int r2 = 0; r2 < 4; ++r2) {
      float a0 = __expf(s0[0][r2] - mrow[0][r2]);
      float a1 = __expf(s0[1][r2] - mrow[0][r2]);
      float a2 = __expf(s0[2][r2] - mrow[0][r2]);
      float a3 = __expf(s0[3][r2] - mrow[0][r2]);
      s0[0][r2] = a0; s0[1][r2] = a1; s0[2][r2] = a2; s0[3][r2] = a3;
      lsum[0][r2] += (a0 + a1) + (a2 + a3);
      float b0 = __expf(s1[0][r2] - mrow[1][r2]);
      float b1 = __expf(s1[1][r2] - mrow[1][r2]);
      float b2 = __expf(s1[2][r2] - mrow[1][r2]);
      float b3 = __expf(s1[3][r2] - mrow[1][r2]);
      s1[0][r2] = b0; s1[1][r2] = b1; s1[2][r2] = b2; s1[3][r2] = b3;
      lsum[1][r2] += (b0 + b1) + (b2 + b3);
    }

    #pragma unroll
    for (int nt = 0; nt < 4; ++nt)
      #pragma unroll
      for (int r2 = 0; r2 < 4; ++r2) {
        pbA[(lq * 4 + r2) * 72 + nt * 16 + lr] = (__bf16)s0[nt][r2];
        pbB[(lq * 4 + r2) * 72 + nt * 16 + lr] = (__bf16)s1[nt][r2];
      }

    #pragma unroll
    for (int k2 = 0; k2 < 2; ++k2) {
      bf16x8_t afrA = *(const bf16x8_t*)(pbA + lr * 72 + k2 * 32 + lq * 8);
      bf16x8_t afrB = *(const bf16x8_t*)(pbB + lr * 72 + k2 * 32 + lq * 8);
      #pragma unroll
      for (int o = 0; o < 8; ++o) {
        bf16x8_t vfr = *(const bf16x8_t*)(
            &Vs[(o * 16 + lr) * 64 + (((k2 * 4 + lq) ^ (lr & 7)) * 8)]);
        Oa[0][o] = mfma_16x16x32(afrA, vfr, Oa[0][o]);
        Oa[1][o] = mfma_16x16x32(afrB, vfr, Oa[1][o]);
      }
    }
    __syncthreads();
  }

  #pragma unroll
  for (int t = 0; t < 2; ++t)
    #pragma unroll
    for (int r2 = 0; r2 < 4; ++r2) {
      float v = lsum[t][r2];
      v += __shfl_xor(v, 1);
      v += __shfl_xor(v, 2);
      v += __shfl_xor(v, 4);
      v += __shfl_xor(v, 8);
      if (lr == 0)
        lpart[bid * 128 + wave * 32 + t * 16 + lq * 4 + r2] = v;
    }

  #pragma unroll
  for (int t = 0; t < 2; ++t)
    #pragma unroll
    for (int o = 0; o < 8; ++o)
      #pragma unroll
      for (int r2 = 0; r2 < 4; ++r2)
        Ofl[(wave * 32 + t * 16 + lq * 4 + r2) * 132 + o * 16 + lr] = Oa[t][o][r2];
  __syncthreads();

  {
    const int row = threadIdx.x >> 1;
    const int cb  = (threadIdx.x & 1) * 64;
    __bf16* dst = Opart + ((size_t)bid * 128 + row) * 128 + cb;
    #pragma unroll
    for (int g2 = 0; g2 < 16; ++g2) {
      float4 f = *(const float4*)(&Ofl[row * 132 + cb + g2 * 4]);
      bf16x4_t o;
      o[0] = (__bf16)f.x; o[1] = (__bf16)f.y; o[2] = (__bf16)f.z; o[3] = (__bf16)f.w;
      *(bf16x4_t*)(dst + g2 * 4) = o;
    }
  }
}

// ---------------------------------------------------------------------------
// Kernel 3: merge the 2 key-halves: out = (O_h0 + O_h1) / (l_h0 + l_h1)
// ---------------------------------------------------------------------------
__global__ __launch_bounds__(256) void merge_kernel(
    const __bf16* __restrict__ Opart, const float* __restrict__ lpart,
    float* __restrict__ out) {
  const int idx = blockIdx.x * 256 + threadIdx.x;   // 524288 threads
  const int row = idx >> 5;                         // global row 0..16383
  const int c4  = (idx & 31) * 4;
  const int b   = row >> 11;
  const int tl  = row & 2047;
  const int jg  = tl >> 7;
  const int lrow = tl & 127;
  const int s0  = b + 8 * (2 * (15 - jg));          // h=0 slot (bid)
  const int s1  = s0 + 8;                           // h=1 slot
  bf16x4_t a = *(const bf16x4_t*)(Opart + ((size_t)s0 * 128 + lrow) * 128 + c4);
  bf16x4_t c = *(const bf16x4_t*)(Opart + ((size_t)s1 * 128 + lrow) * 128 + c4);
  const float l = lpart[s0 * 128 + lrow] + lpart[s1 * 128 + lrow];
  const float inv = 1.0f / l;
  float4 o;
  o.x = ((float)a[0] + (float)c[0]) * inv;
  o.y = ((float)a[1] + (float)c[1]) * inv;
  o.z = ((float)a[2] + (float)c[2]) * inv;
  o.w = ((float)a[3] + (float)c[3]) * inv;
  *(float4*)(out + (size_t)row * HS_N + c4) = o;
}

// ---------------------------------------------------------------------------
extern "C" void kernel_launch(void* const* d_in, const int* in_sizes, int n_in,
                              void* d_out, int out_size, void* d_ws, size_t ws_size,
                              hipStream_t stream) {
  const float* x  = (const float*)d_in[0];
  const float* Wk = (const float*)d_in[1];
  const float* Wq = (const float*)d_in[2];
  const float* Wv = (const float*)d_in[3];
  float* out = (float*)d_out;

  char* ws = (char*)d_ws;
  __bf16* Wb = (__bf16*)ws;                          //   786432 B
  __bf16* Qb = (__bf16*)(ws + 786432);               //  4194304 B
  __bf16* Kb = (__bf16*)(ws + 786432 + 4194304);     //  4194304 B
  __bf16* Vt = (__bf16*)(ws + 786432 + 8388608);     //  4194304 B
  unsigned int* km = (unsigned int*)(ws + 13369344); //       32 B
  __bf16* Opart = (__bf16*)(ws + 13369600);          //  8388608 B (256x128x128)
  float*  lpart = (float*)(ws + 21758208);           //   131072 B

  castw_kernel<<<384, 256, 0, stream>>>(Wk, Wq, Wv, Wb, km);
  proj_kernel<<<512, 256, 0, stream>>>(x, Wb, Qb, Kb, Vt);
  knorm_kernel<<<64, 256, 0, stream>>>(Kb, km);
  attn_kernel<<<256, 256, 0, stream>>>(Qb, Kb, Vt, km, Opart, lpart);
  merge_kernel<<<2048, 256, 0, stream>>>(Opart, lpart, out);
}